// Round 3
// baseline (751.994 us; speedup 1.0000x reference)
//
#include <hip/hip_runtime.h>
#include <hip/hip_bf16.h>
#include <cstdio>
#include <cstdint>

#define TNUM 2048
#define DDIM 768
#define HDIM 3072
#define ENUM 8

typedef __attribute__((ext_vector_type(8))) __bf16 bf16x8;
typedef __attribute__((ext_vector_type(4))) float f32x4;

__device__ __forceinline__ unsigned short f2bf(float f) {
    __bf16 h = (__bf16)f;            // RNE
    unsigned short u;
    __builtin_memcpy(&u, &h, 2);
    return u;
}

// async global->LDS, 16B per lane; LDS dest = wave-uniform base + lane*16
__device__ __forceinline__ void async_cp16(const unsigned short* g, unsigned short* l) {
    __builtin_amdgcn_global_load_lds((const __attribute__((address_space(1))) void*)g,
                                     (__attribute__((address_space(3))) void*)l,
                                     16, 0, 0);
}

// ---------------- cast x -> bf16 ----------------
__global__ void cast_x_kernel(const float* __restrict__ x, unsigned short* __restrict__ xb) {
    int i = (blockIdx.x * 256 + threadIdx.x) * 8;
    float4 a = *(const float4*)(x + i);
    float4 b = *(const float4*)(x + i + 4);
    ushort4 lo = make_ushort4(f2bf(a.x), f2bf(a.y), f2bf(a.z), f2bf(a.w));
    ushort4 hi = make_ushort4(f2bf(b.x), f2bf(b.y), f2bf(b.z), f2bf(b.w));
    *(ushort4*)(xb + i) = lo;
    *(ushort4*)(xb + i + 4) = hi;
}

// ---------------- transpose + cast weights to bf16 [n][k] ----------------
// 64x64 tiles, 576 per z-slice; float4 reads, 128B-coalesced ushort4 writes
__global__ void transw_kernel(const float* __restrict__ W1, const float* __restrict__ W2,
                              const float* __restrict__ Ws1, const float* __restrict__ Ws2,
                              unsigned short* __restrict__ W1t, unsigned short* __restrict__ W2t,
                              unsigned short* __restrict__ Ws1t, unsigned short* __restrict__ Ws2t) {
    int z = blockIdx.z;
    const float* in; unsigned short* out; int R, C;
    if (z < 8)       { in = W1 + (size_t)z * DDIM * HDIM; out = W1t + (size_t)z * HDIM * DDIM; R = DDIM; C = HDIM; }
    else if (z < 16) { int e = z - 8; in = W2 + (size_t)e * HDIM * DDIM; out = W2t + (size_t)e * DDIM * HDIM; R = HDIM; C = DDIM; }
    else if (z == 16){ in = Ws1; out = Ws1t; R = DDIM; C = HDIM; }
    else             { in = Ws2; out = Ws2t; R = HDIM; C = DDIM; }
    int nx = C / 64;
    int id = blockIdx.x;
    int c0 = (id % nx) * 64, r0 = (id / nx) * 64;
    __shared__ unsigned short tile[64][68];
    int tid = threadIdx.x;
    int rr = tid >> 4, c4 = (tid & 15) * 4;
    #pragma unroll
    for (int p = 0; p < 4; p++) {
        int rl = p * 16 + rr;
        float4 v = *(const float4*)(in + (size_t)(r0 + rl) * C + c0 + c4);
        ushort4 u = make_ushort4(f2bf(v.x), f2bf(v.y), f2bf(v.z), f2bf(v.w));
        *(ushort4*)&tile[rl][c4] = u;
    }
    __syncthreads();
    int cr = tid >> 4, r4 = (tid & 15) * 4;
    #pragma unroll
    for (int q = 0; q < 4; q++) {
        int cl = q * 16 + cr;
        ushort4 o = make_ushort4(tile[r4 + 0][cl], tile[r4 + 1][cl], tile[r4 + 2][cl], tile[r4 + 3][cl]);
        *(ushort4*)(out + (size_t)(c0 + cl) * R + r0 + r4) = o;
    }
}

// ---------------- router: one wave per token ----------------
__global__ void router_kernel(const float* __restrict__ x, const float* __restrict__ noise,
                              const float* __restrict__ Wr, const float* __restrict__ br,
                              int* __restrict__ counts, int* __restrict__ list,
                              int* __restrict__ inv, float* __restrict__ tokp) {
    int lane = threadIdx.x & 63;
    int t = blockIdx.x * 4 + (threadIdx.x >> 6);
    float acc[8];
    #pragma unroll
    for (int e = 0; e < 8; e++) acc[e] = 0.f;
    #pragma unroll
    for (int i = 0; i < 12; i++) {
        int d = i * 64 + lane;
        float xv = x[t * DDIM + d];
        float4 w0 = *(const float4*)(Wr + d * 8);
        float4 w1 = *(const float4*)(Wr + d * 8 + 4);
        acc[0] += xv * w0.x; acc[1] += xv * w0.y; acc[2] += xv * w0.z; acc[3] += xv * w0.w;
        acc[4] += xv * w1.x; acc[5] += xv * w1.y; acc[6] += xv * w1.z; acc[7] += xv * w1.w;
    }
    #pragma unroll
    for (int e = 0; e < 8; e++) {
        #pragma unroll
        for (int off2 = 32; off2 >= 1; off2 >>= 1)
            acc[e] += __shfl_xor(acc[e], off2, 64);
    }
    if (lane == 0) {
        float lg[8];
        #pragma unroll
        for (int e = 0; e < 8; e++) lg[e] = acc[e] + br[e] + 0.1f * noise[t * 8 + e];
        int e0 = 0;
        #pragma unroll
        for (int e = 1; e < 8; e++) if (lg[e] > lg[e0]) e0 = e;
        int e1 = -1;
        #pragma unroll
        for (int e = 0; e < 8; e++) if (e != e0 && (e1 < 0 || lg[e] > lg[e1])) e1 = e;
        float m = fmaxf(lg[e0], lg[e1]);
        float p0 = expf(lg[e0] - m), p1 = expf(lg[e1] - m);
        float inv_s = 1.f / (p0 + p1);
        int s0 = atomicAdd(&counts[e0], 1);
        list[e0 * TNUM + s0] = t;
        int s1 = atomicAdd(&counts[e1], 1);
        list[e1 * TNUM + s1] = t;
        inv[t * 2 + 0] = (e0 << 16) | s0;
        inv[t * 2 + 1] = (e1 << 16) | s1;
        tokp[t * 2 + 0] = p0 * inv_s;
        tokp[t * 2 + 1] = p1 * inv_s;
    }
}

// ---------------- prefix offsets + mixing scalars ----------------
__global__ void finalize_kernel(const int* __restrict__ counts, int* __restrict__ offs,
                                const float* __restrict__ alpha, const float* __restrict__ beta,
                                float* __restrict__ scal) {
    int s = 0;
    for (int e = 0; e < 8; e++) { offs[e] = s; s += counts[e]; }
    offs[8] = s;   // == 4096
    float a = alpha[0], b = beta[0];
    float m = fmaxf(a, b);
    float ea = expf(a - m), eb = expf(b - m);
    float inv = 1.f / (ea + eb);
    scal[0] = ea * inv;   // shared expert weight
    scal[1] = eb * inv;   // moe weight
}

// BM=64, BN=128, BK=64 GEMM tile. LDS group layout (group = 16B = one (row, k-oct)):
//   A (512 groups):  G = ks*256 + rc*64 + quad*16 + l15  -> (row = rc*16+l15, k = ks*32+quad*8)
//   B (1024 groups): G = ks*512 + rc*64 + quad*16 + l15
// staging: A round r(0..1): base r*256 + w*64 -> ks=r,   row w*16+l15,           k=r*32+quad*8
//          B round r(0..3): base r*256 + w*64 -> ks=r>>1, row ((r&1)*4+w)*16+l15, k=(r>>1)*32+quad*8
// wave tile 32x64: wm=(w&1)*32, wn=(w>>1)*64; A frags i:0..1 rc=(w&1)*2+i; B frags j:0..3 rc=(w>>1)*4+j

// ---------------- GEMM layer 1: h = leaky(x @ W1[e] + b1[e]) ----------------
__global__ __launch_bounds__(256, 4)
void ffn1_kernel(const unsigned short* __restrict__ xb,
                 const unsigned short* __restrict__ W1t,   // [8][3072][768]
                 const unsigned short* __restrict__ Ws1t,  // [3072][768]
                 const float* __restrict__ b1, const float* __restrict__ bs1,
                 const int* __restrict__ counts, const int* __restrict__ offs,
                 const int* __restrict__ list,
                 unsigned short* __restrict__ hbuf) {      // [6144][3072]
    int z = blockIdx.z;
    int cnt = (z < 8) ? counts[z] : TNUM;
    int m0 = blockIdx.x * 64;
    if (m0 >= cnt) return;
    int n0 = blockIdx.y * 128;
    int hbase = (z < 8) ? offs[z] : 2 * TNUM;
    const unsigned short* Bmat = (z < 8) ? (W1t + (size_t)z * HDIM * DDIM) : Ws1t;
    const float* bias = (z < 8) ? (b1 + z * HDIM) : bs1;

    __shared__ __align__(16) unsigned short As[512 * 8];
    __shared__ __align__(16) unsigned short Bs[1024 * 8];

    int tid = threadIdx.x;
    int w = tid >> 6, lane = tid & 63;
    int l15 = lane & 15, quad = lane >> 4;
    int wm = (w & 1) * 32, wn = (w >> 1) * 64;

    // A staging row (same for both A rounds)
    int rowA = m0 + w * 16 + l15;
    int ra = min(rowA, cnt - 1);
    int tA = (z < 8) ? list[z * TNUM + ra] : ra;

    const unsigned short* gA[2];
    unsigned short* lA[2];
    #pragma unroll
    for (int r = 0; r < 2; r++) {
        gA[r] = xb + (size_t)tA * DDIM + r * 32 + quad * 8;
        lA[r] = As + (r * 256 + w * 64 + quad * 16 + l15 - (quad * 16 + l15)) * 8 + 0; // base only
        lA[r] = As + (r * 256 + w * 64) * 8;
    }
    const unsigned short* gB[4];
    unsigned short* lB[4];
    #pragma unroll
    for (int r = 0; r < 4; r++) {
        int rowB = n0 + ((r & 1) * 4 + w) * 16 + l15;
        gB[r] = Bmat + (size_t)rowB * DDIM + (r >> 1) * 32 + quad * 8;
        lB[r] = Bs + (r * 256 + w * 64) * 8;
    }

    f32x4 zero = {0.f, 0.f, 0.f, 0.f};
    f32x4 acc[2][4];
    #pragma unroll
    for (int i = 0; i < 2; i++)
        #pragma unroll
        for (int j = 0; j < 4; j++) acc[i][j] = zero;

    int rcA = (w & 1) * 2;
    int rcB = (w >> 1) * 4;

    #pragma unroll 1
    for (int kt = 0; kt < DDIM / 64; kt++) {
        int k0 = kt * 64;
        __syncthreads();
        #pragma unroll
        for (int r = 0; r < 2; r++) async_cp16(gA[r] + k0, lA[r]);
        #pragma unroll
        for (int r = 0; r < 4; r++) async_cp16(gB[r] + k0, lB[r]);
        __syncthreads();
        #pragma unroll
        for (int ks = 0; ks < 2; ks++) {
            bf16x8 af[2], bv[4];
            #pragma unroll
            for (int i = 0; i < 2; i++)
                af[i] = *(const bf16x8*)(As + (ks * 256 + (rcA + i) * 64 + quad * 16 + l15) * 8);
            #pragma unroll
            for (int j = 0; j < 4; j++)
                bv[j] = *(const bf16x8*)(Bs + (ks * 512 + (rcB + j) * 64 + quad * 16 + l15) * 8);
            #pragma unroll
            for (int i = 0; i < 2; i++)
                #pragma unroll
                for (int j = 0; j < 4; j++)
                    acc[i][j] = __builtin_amdgcn_mfma_f32_16x16x32_bf16(af[i], bv[j], acc[i][j], 0, 0, 0);
        }
    }

    #pragma unroll
    for (int i = 0; i < 2; i++) {
        int rbase = m0 + wm + i * 16 + quad * 4;
        #pragma unroll
        for (int j = 0; j < 4; j++) {
            int gc = n0 + wn + j * 16 + l15;
            float bvl = bias[gc];
            #pragma unroll
            for (int r = 0; r < 4; r++) {
                int gr = rbase + r;
                if (gr < cnt) {
                    float v = acc[i][j][r] + bvl;
                    v = v > 0.f ? v : 0.01f * v;
                    hbuf[(size_t)(hbase + gr) * HDIM + gc] = f2bf(v);
                }
            }
        }
    }
}

// ---------------- GEMM layer 2: ybuf[kh] = h @ W2[e] (plain stores) ----------------
__global__ __launch_bounds__(256, 4)
void ffn2_kernel(const unsigned short* __restrict__ hbuf,
                 const unsigned short* __restrict__ W2t,   // [8][768][3072]
                 const unsigned short* __restrict__ Ws2t,  // [768][3072]
                 const int* __restrict__ counts, const int* __restrict__ offs,
                 float* __restrict__ ybuf) {               // [2][6144][768]
    int zz = blockIdx.z;
    int z = zz % 9, kh = zz / 9;
    int cnt = (z < 8) ? counts[z] : TNUM;
    int m0 = blockIdx.x * 64;
    if (m0 >= cnt) return;
    int n0 = blockIdx.y * 128;
    int hbase = (z < 8) ? offs[z] : 2 * TNUM;
    const unsigned short* Bmat = (z < 8) ? (W2t + (size_t)z * DDIM * HDIM) : Ws2t;

    __shared__ __align__(16) unsigned short As[512 * 8];
    __shared__ __align__(16) unsigned short Bs[1024 * 8];

    int tid = threadIdx.x;
    int w = tid >> 6, lane = tid & 63;
    int l15 = lane & 15, quad = lane >> 4;
    int wm = (w & 1) * 32, wn = (w >> 1) * 64;

    int rowA = m0 + w * 16 + l15;
    int ra = min(rowA, cnt - 1);
    int kbase = kh * (HDIM / 2);

    const unsigned short* gA[2];
    unsigned short* lA[2];
    #pragma unroll
    for (int r = 0; r < 2; r++) {
        gA[r] = hbuf + (size_t)(hbase + ra) * HDIM + kbase + r * 32 + quad * 8;
        lA[r] = As + (r * 256 + w * 64) * 8;
    }
    const unsigned short* gB[4];
    unsigned short* lB[4];
    #pragma unroll
    for (int r = 0; r < 4; r++) {
        int rowB = n0 + ((r & 1) * 4 + w) * 16 + l15;
        gB[r] = Bmat + (size_t)rowB * HDIM + kbase + (r >> 1) * 32 + quad * 8;
        lB[r] = Bs + (r * 256 + w * 64) * 8;
    }

    f32x4 zero = {0.f, 0.f, 0.f, 0.f};
    f32x4 acc[2][4];
    #pragma unroll
    for (int i = 0; i < 2; i++)
        #pragma unroll
        for (int j = 0; j < 4; j++) acc[i][j] = zero;

    int rcA = (w & 1) * 2;
    int rcB = (w >> 1) * 4;

    #pragma unroll 1
    for (int kt = 0; kt < (HDIM / 2) / 64; kt++) {
        int k0 = kt * 64;
        __syncthreads();
        #pragma unroll
        for (int r = 0; r < 2; r++) async_cp16(gA[r] + k0, lA[r]);
        #pragma unroll
        for (int r = 0; r < 4; r++) async_cp16(gB[r] + k0, lB[r]);
        __syncthreads();
        #pragma unroll
        for (int ks = 0; ks < 2; ks++) {
            bf16x8 af[2], bv[4];
            #pragma unroll
            for (int i = 0; i < 2; i++)
                af[i] = *(const bf16x8*)(As + (ks * 256 + (rcA + i) * 64 + quad * 16 + l15) * 8);
            #pragma unroll
            for (int j = 0; j < 4; j++)
                bv[j] = *(const bf16x8*)(Bs + (ks * 512 + (rcB + j) * 64 + quad * 16 + l15) * 8);
            #pragma unroll
            for (int i = 0; i < 2; i++)
                #pragma unroll
                for (int j = 0; j < 4; j++)
                    acc[i][j] = __builtin_amdgcn_mfma_f32_16x16x32_bf16(af[i], bv[j], acc[i][j], 0, 0, 0);
        }
    }

    float* yb = ybuf + (size_t)kh * 6144 * DDIM;
    #pragma unroll
    for (int i = 0; i < 2; i++) {
        int rbase = m0 + wm + i * 16 + quad * 4;
        #pragma unroll
        for (int r = 0; r < 4; r++) {
            int gr = rbase + r;
            if (gr >= cnt) continue;
            float* orow = yb + (size_t)(hbase + gr) * DDIM + n0 + wn;
            #pragma unroll
            for (int j = 0; j < 4; j++)
                orow[j * 16 + l15] = acc[i][j][r];
        }
    }
}

// ---------------- final mix: gather expert rows + shared, apply gates/biases ----------------
__global__ void mix_kernel(const float* __restrict__ ybuf, const int* __restrict__ inv,
                           const float* __restrict__ tokp, const int* __restrict__ offs,
                           const float* __restrict__ b2, const float* __restrict__ bs2,
                           const float* __restrict__ scal, float* __restrict__ out) {
    int t = blockIdx.x;
    int c = threadIdx.x * 4;          // blockDim = 192 -> covers 768
    int i0 = inv[t * 2 + 0], i1 = inv[t * 2 + 1];
    int e0 = i0 >> 16, sl0 = i0 & 0xFFFF;
    int e1 = i1 >> 16, sl1 = i1 & 0xFFFF;
    float p0 = tokp[t * 2 + 0], p1 = tokp[t * 2 + 1];
    float ws = scal[0], wmx = scal[1];
    size_t rA = (size_t)(offs[e0] + sl0) * DDIM + c;
    size_t rB = (size_t)(offs[e1] + sl1) * DDIM + c;
    size_t rS = (size_t)(2 * TNUM + t) * DDIM + c;
    const float* y0 = ybuf;
    const float* y1 = ybuf + (size_t)6144 * DDIM;
    float4 vA0 = *(const float4*)(y0 + rA);
    float4 vA1 = *(const float4*)(y1 + rA);
    float4 vB0 = *(const float4*)(y0 + rB);
    float4 vB1 = *(const float4*)(y1 + rB);
    float4 vS0 = *(const float4*)(y0 + rS);
    float4 vS1 = *(const float4*)(y1 + rS);
    float4 bA = *(const float4*)(b2 + e0 * DDIM + c);
    float4 bB = *(const float4*)(b2 + e1 * DDIM + c);
    float4 bS = *(const float4*)(bs2 + c);
    float4 o;
    o.x = ws * (vS0.x + vS1.x + bS.x) + wmx * (p0 * (vA0.x + vA1.x + bA.x) + p1 * (vB0.x + vB1.x + bB.x));
    o.y = ws * (vS0.y + vS1.y + bS.y) + wmx * (p0 * (vA0.y + vA1.y + bA.y) + p1 * (vB0.y + vB1.y + bB.y));
    o.z = ws * (vS0.z + vS1.z + bS.z) + wmx * (p0 * (vA0.z + vA1.z + bA.z) + p1 * (vB0.z + vB1.z + bB.z));
    o.w = ws * (vS0.w + vS1.w + bS.w) + wmx * (p0 * (vA0.w + vA1.w + bA.w) + p1 * (vB0.w + vB1.w + bB.w));
    *(float4*)(out + (size_t)t * DDIM + c) = o;
}

extern "C" void kernel_launch(void* const* d_in, const int* in_sizes, int n_in,
                              void* d_out, int out_size, void* d_ws, size_t ws_size,
                              hipStream_t stream) {
    const float* x     = (const float*)d_in[0];
    const float* noise = (const float*)d_in[1];
    const float* Wr    = (const float*)d_in[2];
    const float* br    = (const float*)d_in[3];
    const float* W1    = (const float*)d_in[4];
    const float* b1    = (const float*)d_in[5];
    const float* W2    = (const float*)d_in[6];
    const float* b2    = (const float*)d_in[7];
    const float* Ws1   = (const float*)d_in[8];
    const float* bs1   = (const float*)d_in[9];
    const float* Ws2   = (const float*)d_in[10];
    const float* bs2   = (const float*)d_in[11];
    const float* alpha = (const float*)d_in[12];
    const float* beta  = (const float*)d_in[13];

    char* ws = (char*)d_ws;
    size_t off = 0;
    auto alloc = [&](size_t bytes) -> char* {
        char* p = ws + off;
        off = (off + bytes + 255) & ~(size_t)255;
        return p;
    };
    int*   counts = (int*)  alloc(ENUM * 4);
    int*   offs   = (int*)  alloc(16 * 4);
    float* scal   = (float*)alloc(2 * 4);
    int*   list   = (int*)  alloc((size_t)ENUM * TNUM * 4);
    int*   inv    = (int*)  alloc((size_t)TNUM * 2 * 4);
    float* tokp   = (float*)alloc((size_t)TNUM * 2 * 4);
    unsigned short* xb   = (unsigned short*)alloc((size_t)TNUM * DDIM * 2);
    unsigned short* W1t  = (unsigned short*)alloc((size_t)ENUM * HDIM * DDIM * 2);  // 36 MB
    unsigned short* Ws1t = (unsigned short*)alloc((size_t)HDIM * DDIM * 2);         // 4.5 MB (adjacent)
    unsigned short* W2t  = (unsigned short*)alloc((size_t)ENUM * DDIM * HDIM * 2);
    unsigned short* Ws2t = (unsigned short*)alloc((size_t)DDIM * HDIM * 2);
    unsigned short* hbuf = (unsigned short*)alloc((size_t)(3 * TNUM) * HDIM * 2);
    // ybuf (2*6144*768*4 = 37.75 MB) aliases W1t+Ws1t (40.5 MB contiguous): last reader of
    // W1t/Ws1t is ffn1; ffn2 writes ybuf strictly after on the same stream.
    float* ybuf = (float*)W1t;
    if (off > ws_size) {
        fprintf(stderr, "kernel_launch: workspace too small (need %zu, have %zu)\n", off, ws_size);
        return;
    }

    hipMemsetAsync(counts, 0, ENUM * 4, stream);

    cast_x_kernel<<<dim3((TNUM * DDIM / 8) / 256), dim3(256), 0, stream>>>(x, xb);
    transw_kernel<<<dim3(576, 1, 18), dim3(256), 0, stream>>>(W1, W2, Ws1, Ws2, W1t, W2t, Ws1t, Ws2t);
    router_kernel<<<dim3(TNUM / 4), dim3(256), 0, stream>>>(x, noise, Wr, br, counts, list, inv, tokp);
    finalize_kernel<<<dim3(1), dim3(1), 0, stream>>>(counts, offs, alpha, beta, scal);
    ffn1_kernel<<<dim3(32, 24, 9), dim3(256), 0, stream>>>(xb, W1t, Ws1t, b1, bs1, counts, offs, list, hbuf);
    ffn2_kernel<<<dim3(32, 6, 18), dim3(256), 0, stream>>>(hbuf, W2t, Ws2t, counts, offs, ybuf);
    mix_kernel<<<dim3(TNUM), dim3(192), 0, stream>>>(ybuf, inv, tokp, offs, b2, bs2, scal, (float*)d_out);
}

// Round 4
// 491.734 us; speedup vs baseline: 1.5293x; 1.5293x over previous
//
#include <hip/hip_runtime.h>
#include <hip/hip_bf16.h>
#include <cstdio>
#include <cstdint>

#define TNUM 2048
#define DDIM 768
#define HDIM 3072
#define ENUM 8

typedef __attribute__((ext_vector_type(8))) __bf16 bf16x8;
typedef __attribute__((ext_vector_type(4))) float f32x4;
typedef __attribute__((ext_vector_type(8))) unsigned short ushort8_t;

__device__ __forceinline__ unsigned short f2bf(float f) {
    __bf16 h = (__bf16)f;            // RNE
    unsigned short u;
    __builtin_memcpy(&u, &h, 2);
    return u;
}

// async global->LDS, 16B per lane; LDS dest = wave-uniform base + lane*16
__device__ __forceinline__ void async_cp16(const unsigned short* g, unsigned short* l) {
    __builtin_amdgcn_global_load_lds((const __attribute__((address_space(1))) void*)g,
                                     (__attribute__((address_space(3))) void*)l,
                                     16, 0, 0);
}

// ---------------- cast x -> bf16 ----------------
__global__ void cast_x_kernel(const float* __restrict__ x, unsigned short* __restrict__ xb) {
    int i = (blockIdx.x * 256 + threadIdx.x) * 8;
    float4 a = *(const float4*)(x + i);
    float4 b = *(const float4*)(x + i + 4);
    ushort4 lo = make_ushort4(f2bf(a.x), f2bf(a.y), f2bf(a.z), f2bf(a.w));
    ushort4 hi = make_ushort4(f2bf(b.x), f2bf(b.y), f2bf(b.z), f2bf(b.w));
    *(ushort4*)(xb + i) = lo;
    *(ushort4*)(xb + i + 4) = hi;
}

// ---------------- transpose + cast weights to bf16 [n][k] ----------------
// 128x128 tiles; stage fp32->bf16 into transposed LDS tile, read out coalesced.
// Global reads: 256B runs per 16 lanes. Global writes: 256B runs per 16 lanes.
__global__ __launch_bounds__(256)
void transw_kernel(const float* __restrict__ W1, const float* __restrict__ W2,
                   const float* __restrict__ Ws1, const float* __restrict__ Ws2,
                   unsigned short* __restrict__ W1t, unsigned short* __restrict__ W2t,
                   unsigned short* __restrict__ Ws1t, unsigned short* __restrict__ Ws2t) {
    int z = blockIdx.z;
    const float* in; unsigned short* out; int R, C;
    if (z < 8)       { in = W1 + (size_t)z * DDIM * HDIM; out = W1t + (size_t)z * HDIM * DDIM; R = DDIM; C = HDIM; }
    else if (z < 16) { int e = z - 8; in = W2 + (size_t)e * HDIM * DDIM; out = W2t + (size_t)e * DDIM * HDIM; R = HDIM; C = DDIM; }
    else if (z == 16){ in = Ws1; out = Ws1t; R = DDIM; C = HDIM; }
    else             { in = Ws2; out = Ws2t; R = HDIM; C = DDIM; }
    int nx = C / 128;
    int c0 = (blockIdx.x % nx) * 128, r0 = (blockIdx.x / nx) * 128;
    // tile_T[c][r] transposed, pitch 136 halfwords (rows 16B-aligned for b128 reads)
    __shared__ unsigned short tileT[128 * 136];
    int tid = threadIdx.x;
    int l15 = tid & 15;
    // stage: 16 passes, each: 16-lane-contiguous float4 run of one input row-half
    #pragma unroll
    for (int p = 0; p < 16; p++) {
        int unit = p * 16 + (tid >> 4);      // 0..255 : (row, half)
        int r = unit >> 1, hf = unit & 1;
        int cb = hf * 64 + l15 * 4;
        float4 v = *(const float4*)(in + (size_t)(r0 + r) * C + c0 + cb);
        tileT[(cb + 0) * 136 + r] = f2bf(v.x);
        tileT[(cb + 1) * 136 + r] = f2bf(v.y);
        tileT[(cb + 2) * 136 + r] = f2bf(v.z);
        tileT[(cb + 3) * 136 + r] = f2bf(v.w);
    }
    __syncthreads();
    // write out: 8 passes, each: 16-lane ushort8 run = full 256B output row
    #pragma unroll
    for (int p = 0; p < 8; p++) {
        int cc = p * 16 + (tid >> 4);        // output row (= input col) 0..127
        ushort8_t u = *(const ushort8_t*)&tileT[cc * 136 + l15 * 8];
        *(ushort8_t*)(out + (size_t)(c0 + cc) * R + r0 + l15 * 8) = u;
    }
}

// ---------------- router: one wave per token ----------------
__global__ void router_kernel(const float* __restrict__ x, const float* __restrict__ noise,
                              const float* __restrict__ Wr, const float* __restrict__ br,
                              int* __restrict__ counts, int* __restrict__ list,
                              int* __restrict__ inv, float* __restrict__ tokp) {
    int lane = threadIdx.x & 63;
    int t = blockIdx.x * 4 + (threadIdx.x >> 6);
    float acc[8];
    #pragma unroll
    for (int e = 0; e < 8; e++) acc[e] = 0.f;
    #pragma unroll
    for (int i = 0; i < 12; i++) {
        int d = i * 64 + lane;
        float xv = x[t * DDIM + d];
        float4 w0 = *(const float4*)(Wr + d * 8);
        float4 w1 = *(const float4*)(Wr + d * 8 + 4);
        acc[0] += xv * w0.x; acc[1] += xv * w0.y; acc[2] += xv * w0.z; acc[3] += xv * w0.w;
        acc[4] += xv * w1.x; acc[5] += xv * w1.y; acc[6] += xv * w1.z; acc[7] += xv * w1.w;
    }
    #pragma unroll
    for (int e = 0; e < 8; e++) {
        #pragma unroll
        for (int off2 = 32; off2 >= 1; off2 >>= 1)
            acc[e] += __shfl_xor(acc[e], off2, 64);
    }
    if (lane == 0) {
        float lg[8];
        #pragma unroll
        for (int e = 0; e < 8; e++) lg[e] = acc[e] + br[e] + 0.1f * noise[t * 8 + e];
        int e0 = 0;
        #pragma unroll
        for (int e = 1; e < 8; e++) if (lg[e] > lg[e0]) e0 = e;
        int e1 = -1;
        #pragma unroll
        for (int e = 0; e < 8; e++) if (e != e0 && (e1 < 0 || lg[e] > lg[e1])) e1 = e;
        float m = fmaxf(lg[e0], lg[e1]);
        float p0 = expf(lg[e0] - m), p1 = expf(lg[e1] - m);
        float inv_s = 1.f / (p0 + p1);
        int s0 = atomicAdd(&counts[e0], 1);
        list[e0 * TNUM + s0] = t;
        int s1 = atomicAdd(&counts[e1], 1);
        list[e1 * TNUM + s1] = t;
        inv[t * 2 + 0] = (e0 << 16) | s0;
        inv[t * 2 + 1] = (e1 << 16) | s1;
        tokp[t * 2 + 0] = p0 * inv_s;
        tokp[t * 2 + 1] = p1 * inv_s;
    }
}

// ---------------- prefix offsets + mixing scalars ----------------
__global__ void finalize_kernel(const int* __restrict__ counts, int* __restrict__ offs,
                                const float* __restrict__ alpha, const float* __restrict__ beta,
                                float* __restrict__ scal) {
    int s = 0;
    for (int e = 0; e < 8; e++) { offs[e] = s; s += counts[e]; }
    offs[8] = s;   // == 4096
    float a = alpha[0], b = beta[0];
    float m = fmaxf(a, b);
    float ea = expf(a - m), eb = expf(b - m);
    float inv = 1.f / (ea + eb);
    scal[0] = ea * inv;   // shared expert weight
    scal[1] = eb * inv;   // moe weight
}

// BK=32 LDS tile layout (16B group = one (row, k-oct)):
//   group G = rc*64 + quad*16 + l15  ->  (row = rc*16+l15, k = quad*8)
// staging round r, wave w: base group (r*4+w)*64; lane lands at +quad*16+l15. Conflict-free.
// XCD-job grids: gridDim.x = 8 -> blockIdx.x == XCD (linear dispatch % 8 heuristic);
// blockIdx.z picks which of the slot's jobs; blockIdx.y enumerates M/N tiles in the job.

// ---------------- GEMM layer 1: h = leaky(x @ W1[e] + b1[e]) ----------------
// BM=128, BN=128, BK=32, double-buffered. 20 jobs:
//   j<16: expert e=j>>1, n-half nh=j&1 (A 0.75MB + B 2.25MB in one XCD L2)
//   j>=16: shared quadrant (mh, nh)
__global__ __launch_bounds__(256, 4)
void ffn1_kernel(const unsigned short* __restrict__ xb,
                 const unsigned short* __restrict__ W1t,   // [8][3072][768]
                 const unsigned short* __restrict__ Ws1t,  // [3072][768]
                 const float* __restrict__ b1, const float* __restrict__ bs1,
                 const int* __restrict__ counts, const int* __restrict__ offs,
                 const int* __restrict__ list,
                 unsigned short* __restrict__ hbuf) {      // [6144][3072]
    int j = blockIdx.z * 8 + blockIdx.x;
    if (j >= 20) return;
    int y = blockIdx.y;
    int mt = y / 12, ntl = y % 12;
    int cnt, hbase, n0, m0;
    const unsigned short* Bmat;
    const float* bias;
    const int* lst = nullptr;
    if (j < 16) {
        int e = j >> 1, nh = j & 1;
        cnt = counts[e];
        m0 = mt * 128;
        if (m0 >= cnt) return;
        hbase = offs[e];
        n0 = nh * 1536 + ntl * 128;
        Bmat = W1t + (size_t)e * HDIM * DDIM;
        bias = b1 + e * HDIM;
        lst = list + e * TNUM;
    } else {
        int q = j - 16;
        int mh = q >> 1, nh = q & 1;
        if (mt >= 8) return;
        m0 = mh * 1024 + mt * 128;
        cnt = 1 << 30;
        hbase = 2 * TNUM;
        n0 = nh * 1536 + ntl * 128;
        Bmat = Ws1t;
        bias = bs1;
    }

    __shared__ __align__(16) unsigned short As[2][512 * 8];
    __shared__ __align__(16) unsigned short Bs[2][512 * 8];

    int tid = threadIdx.x;
    int w = tid >> 6, lane = tid & 63;
    int l15 = lane & 15, quad = lane >> 4;
    int wm = (w & 1) * 64, wn = (w >> 1) * 64;

    const unsigned short* gA[2];
    const unsigned short* gB[2];
    int ldsoff[2];
    #pragma unroll
    for (int r = 0; r < 2; r++) {
        int rc = r * 4 + w;
        int rowl = rc * 16 + l15;
        int row;
        if (lst) row = lst[min(m0 + rowl, cnt - 1)];
        else     row = m0 + rowl;
        gA[r] = xb + (size_t)row * DDIM + quad * 8;
        gB[r] = Bmat + (size_t)(n0 + rowl) * DDIM + quad * 8;
        ldsoff[r] = rc * 512;     // halfword offset of group base
    }

    f32x4 zero = {0.f, 0.f, 0.f, 0.f};
    f32x4 acc[4][4];
    #pragma unroll
    for (int i = 0; i < 4; i++)
        #pragma unroll
        for (int jj = 0; jj < 4; jj++) acc[i][jj] = zero;

    int rcA = (w & 1) * 4;
    int rcB = (w >> 1) * 4;

    // prologue: issue tile 0 into buffer 0
    #pragma unroll
    for (int r = 0; r < 2; r++) {
        async_cp16(gA[r], &As[0][ldsoff[r]]);
        async_cp16(gB[r], &Bs[0][ldsoff[r]]);
    }

    #pragma unroll 1
    for (int kt = 0; kt < DDIM / 32; kt++) {
        __syncthreads();                       // drains tile-kt loads
        int cur = kt & 1;
        if (kt + 1 < DDIM / 32) {
            int ko = (kt + 1) * 32;
            #pragma unroll
            for (int r = 0; r < 2; r++) {
                async_cp16(gA[r] + ko, &As[cur ^ 1][ldsoff[r]]);
                async_cp16(gB[r] + ko, &Bs[cur ^ 1][ldsoff[r]]);
            }
        }
        bf16x8 af[4], bv[4];
        #pragma unroll
        for (int i = 0; i < 4; i++)
            af[i] = *(const bf16x8*)&As[cur][((rcA + i) * 64 + quad * 16 + l15) * 8];
        #pragma unroll
        for (int jj = 0; jj < 4; jj++)
            bv[jj] = *(const bf16x8*)&Bs[cur][((rcB + jj) * 64 + quad * 16 + l15) * 8];
        #pragma unroll
        for (int i = 0; i < 4; i++)
            #pragma unroll
            for (int jj = 0; jj < 4; jj++)
                acc[i][jj] = __builtin_amdgcn_mfma_f32_16x16x32_bf16(af[i], bv[jj], acc[i][jj], 0, 0, 0);
    }

    #pragma unroll
    for (int i = 0; i < 4; i++) {
        int rbase = m0 + wm + i * 16 + quad * 4;
        #pragma unroll
        for (int jj = 0; jj < 4; jj++) {
            int gc = n0 + wn + jj * 16 + l15;
            float bvl = bias[gc];
            #pragma unroll
            for (int r = 0; r < 4; r++) {
                int gr = rbase + r;
                if (gr < cnt) {
                    float v = acc[i][jj][r] + bvl;
                    v = v > 0.f ? v : 0.01f * v;
                    hbuf[(size_t)(hbase + gr) * HDIM + gc] = f2bf(v);
                }
            }
        }
    }
}

// ---------------- GEMM layer 2: ybuf[kh] = h @ W2[e] (plain fp32 stores) ----------------
// BM=64, BN=128, BK=32, double-buffered. 24 jobs:
//   j<16: expert e=j>>1, kh=j&1 (A 1.5MB + B-half 2.25MB in one XCD L2)
//   j>=16: shared (mh 0..3, kh)
__global__ __launch_bounds__(256, 4)
void ffn2_kernel(const unsigned short* __restrict__ hbuf,
                 const unsigned short* __restrict__ W2t,   // [8][768][3072]
                 const unsigned short* __restrict__ Ws2t,  // [768][3072]
                 const int* __restrict__ counts, const int* __restrict__ offs,
                 float* __restrict__ ybuf) {               // [2][6144][768]
    int j = blockIdx.z * 8 + blockIdx.x;
    int y = blockIdx.y;
    int mt = y / 6, ntl = y % 6;
    int cnt, hbase, m0, kh;
    const unsigned short* Bmat;
    if (j < 16) {
        int e = j >> 1; kh = j & 1;
        cnt = counts[e];
        m0 = mt * 64;
        if (m0 >= cnt) return;
        hbase = offs[e];
        Bmat = W2t + (size_t)e * DDIM * HDIM;
    } else {
        int q = j - 16;
        int mh = q >> 1; kh = q & 1;
        if (mt >= 8) return;
        m0 = mh * 512 + mt * 64;
        cnt = 1 << 30;
        hbase = 2 * TNUM;
        Bmat = Ws2t;
    }
    int n0 = ntl * 128;
    int kbase = kh * (HDIM / 2);

    __shared__ __align__(16) unsigned short As[2][256 * 8];
    __shared__ __align__(16) unsigned short Bs[2][512 * 8];

    int tid = threadIdx.x;
    int w = tid >> 6, lane = tid & 63;
    int l15 = lane & 15, quad = lane >> 4;
    int wm = (w & 1) * 32, wn = (w >> 1) * 64;

    // A: one round, rc = w, rows m0 + w*16 + l15 (clamped)
    int rowl = w * 16 + l15;
    int ra = (j < 16) ? min(m0 + rowl, cnt - 1) : (m0 + rowl);
    const unsigned short* gA0 = hbuf + (size_t)(hbase + ra) * HDIM + kbase + quad * 8;
    unsigned short* lA0base0 = (unsigned short*)&As[0][w * 512];
    unsigned short* lA0base1 = (unsigned short*)&As[1][w * 512];

    const unsigned short* gB[2];
    int ldsoffB[2];
    #pragma unroll
    for (int r = 0; r < 2; r++) {
        int rc = r * 4 + w;
        gB[r] = Bmat + (size_t)(n0 + rc * 16 + l15) * HDIM + kbase + quad * 8;
        ldsoffB[r] = rc * 512;
    }

    f32x4 zero = {0.f, 0.f, 0.f, 0.f};
    f32x4 acc[2][4];
    #pragma unroll
    for (int i = 0; i < 2; i++)
        #pragma unroll
        for (int jj = 0; jj < 4; jj++) acc[i][jj] = zero;

    int rcA = (w & 1) * 2;
    int rcB = (w >> 1) * 4;

    // prologue
    async_cp16(gA0, lA0base0);
    #pragma unroll
    for (int r = 0; r < 2; r++) async_cp16(gB[r], &Bs[0][ldsoffB[r]]);

    const int KT = (HDIM / 2) / 32;   // 48
    #pragma unroll 1
    for (int kt = 0; kt < KT; kt++) {
        __syncthreads();
        int cur = kt & 1;
        if (kt + 1 < KT) {
            int ko = (kt + 1) * 32;
            async_cp16(gA0 + ko, cur ? lA0base0 : lA0base1);
            #pragma unroll
            for (int r = 0; r < 2; r++) async_cp16(gB[r] + ko, &Bs[cur ^ 1][ldsoffB[r]]);
        }
        bf16x8 af[2], bv[4];
        #pragma unroll
        for (int i = 0; i < 2; i++)
            af[i] = *(const bf16x8*)&As[cur][((rcA + i) * 64 + quad * 16 + l15) * 8];
        #pragma unroll
        for (int jj = 0; jj < 4; jj++)
            bv[jj] = *(const bf16x8*)&Bs[cur][((rcB + jj) * 64 + quad * 16 + l15) * 8];
        #pragma unroll
        for (int i = 0; i < 2; i++)
            #pragma unroll
            for (int jj = 0; jj < 4; jj++)
                acc[i][jj] = __builtin_amdgcn_mfma_f32_16x16x32_bf16(af[i], bv[jj], acc[i][jj], 0, 0, 0);
    }

    float* yb = ybuf + (size_t)kh * 6144 * DDIM;
    #pragma unroll
    for (int i = 0; i < 2; i++) {
        int rbase = m0 + wm + i * 16 + quad * 4;
        #pragma unroll
        for (int r = 0; r < 4; r++) {
            int gr = rbase + r;
            if (gr >= cnt) continue;
            float* orow = yb + (size_t)(hbase + gr) * DDIM + n0 + wn;
            #pragma unroll
            for (int jj = 0; jj < 4; jj++)
                orow[jj * 16 + l15] = acc[i][jj][r];
        }
    }
}

// ---------------- final mix: gather expert rows + shared, apply gates/biases ----------------
__global__ void mix_kernel(const float* __restrict__ ybuf, const int* __restrict__ inv,
                           const float* __restrict__ tokp, const int* __restrict__ offs,
                           const float* __restrict__ b2, const float* __restrict__ bs2,
                           const float* __restrict__ scal, float* __restrict__ out) {
    int t = blockIdx.x;
    int c = threadIdx.x * 4;          // blockDim = 192 -> covers 768
    int i0 = inv[t * 2 + 0], i1 = inv[t * 2 + 1];
    int e0 = i0 >> 16, sl0 = i0 & 0xFFFF;
    int e1 = i1 >> 16, sl1 = i1 & 0xFFFF;
    float p0 = tokp[t * 2 + 0], p1 = tokp[t * 2 + 1];
    float ws = scal[0], wmx = scal[1];
    size_t rA = (size_t)(offs[e0] + sl0) * DDIM + c;
    size_t rB = (size_t)(offs[e1] + sl1) * DDIM + c;
    size_t rS = (size_t)(2 * TNUM + t) * DDIM + c;
    const float* y0 = ybuf;
    const float* y1 = ybuf + (size_t)6144 * DDIM;
    float4 vA0 = *(const float4*)(y0 + rA);
    float4 vA1 = *(const float4*)(y1 + rA);
    float4 vB0 = *(const float4*)(y0 + rB);
    float4 vB1 = *(const float4*)(y1 + rB);
    float4 vS0 = *(const float4*)(y0 + rS);
    float4 vS1 = *(const float4*)(y1 + rS);
    float4 bA = *(const float4*)(b2 + e0 * DDIM + c);
    float4 bB = *(const float4*)(b2 + e1 * DDIM + c);
    float4 bS = *(const float4*)(bs2 + c);
    float4 o;
    o.x = ws * (vS0.x + vS1.x + bS.x) + wmx * (p0 * (vA0.x + vA1.x + bA.x) + p1 * (vB0.x + vB1.x + bB.x));
    o.y = ws * (vS0.y + vS1.y + bS.y) + wmx * (p0 * (vA0.y + vA1.y + bA.y) + p1 * (vB0.y + vB1.y + bB.y));
    o.z = ws * (vS0.z + vS1.z + bS.z) + wmx * (p0 * (vA0.z + vA1.z + bA.z) + p1 * (vB0.z + vB1.z + bB.z));
    o.w = ws * (vS0.w + vS1.w + bS.w) + wmx * (p0 * (vA0.w + vA1.w + bA.w) + p1 * (vB0.w + vB1.w + bB.w));
    *(float4*)(out + (size_t)t * DDIM + c) = o;
}

extern "C" void kernel_launch(void* const* d_in, const int* in_sizes, int n_in,
                              void* d_out, int out_size, void* d_ws, size_t ws_size,
                              hipStream_t stream) {
    const float* x     = (const float*)d_in[0];
    const float* noise = (const float*)d_in[1];
    const float* Wr    = (const float*)d_in[2];
    const float* br    = (const float*)d_in[3];
    const float* W1    = (const float*)d_in[4];
    const float* b1    = (const float*)d_in[5];
    const float* W2    = (const float*)d_in[6];
    const float* b2    = (const float*)d_in[7];
    const float* Ws1   = (const float*)d_in[8];
    const float* bs1   = (const float*)d_in[9];
    const float* Ws2   = (const float*)d_in[10];
    const float* bs2   = (const float*)d_in[11];
    const float* alpha = (const float*)d_in[12];
    const float* beta  = (const float*)d_in[13];

    char* ws = (char*)d_ws;
    size_t off = 0;
    auto alloc = [&](size_t bytes) -> char* {
        char* p = ws + off;
        off = (off + bytes + 255) & ~(size_t)255;
        return p;
    };
    int*   counts = (int*)  alloc(ENUM * 4);
    int*   offs   = (int*)  alloc(16 * 4);
    float* scal   = (float*)alloc(2 * 4);
    int*   list   = (int*)  alloc((size_t)ENUM * TNUM * 4);
    int*   inv    = (int*)  alloc((size_t)TNUM * 2 * 4);
    float* tokp   = (float*)alloc((size_t)TNUM * 2 * 4);
    unsigned short* xb   = (unsigned short*)alloc((size_t)TNUM * DDIM * 2);
    unsigned short* W1t  = (unsigned short*)alloc((size_t)ENUM * HDIM * DDIM * 2);  // 36 MB
    unsigned short* Ws1t = (unsigned short*)alloc((size_t)HDIM * DDIM * 2);         // 4.5 MB (adjacent)
    unsigned short* W2t  = (unsigned short*)alloc((size_t)ENUM * DDIM * HDIM * 2);
    unsigned short* Ws2t = (unsigned short*)alloc((size_t)DDIM * HDIM * 2);
    unsigned short* hbuf = (unsigned short*)alloc((size_t)(3 * TNUM) * HDIM * 2);
    // ybuf (2*6144*768*4 = 37.75 MB) aliases W1t+Ws1t (40.5 MB contiguous): last reader of
    // W1t/Ws1t is ffn1; ffn2 writes ybuf strictly after on the same stream.
    float* ybuf = (float*)W1t;
    if (off > ws_size) {
        fprintf(stderr, "kernel_launch: workspace too small (need %zu, have %zu)\n", off, ws_size);
        return;
    }

    hipMemsetAsync(counts, 0, ENUM * 4, stream);

    cast_x_kernel<<<dim3((TNUM * DDIM / 8) / 256), dim3(256), 0, stream>>>(x, xb);
    transw_kernel<<<dim3(144, 1, 18), dim3(256), 0, stream>>>(W1, W2, Ws1, Ws2, W1t, W2t, Ws1t, Ws2t);
    router_kernel<<<dim3(TNUM / 4), dim3(256), 0, stream>>>(x, noise, Wr, br, counts, list, inv, tokp);
    finalize_kernel<<<dim3(1), dim3(1), 0, stream>>>(counts, offs, alpha, beta, scal);
    // XCD-job grids: x = 8 (XCD slot), y = tiles within job, z = job layer
    ffn1_kernel<<<dim3(8, 192, 3), dim3(256), 0, stream>>>(xb, W1t, Ws1t, b1, bs1, counts, offs, list, hbuf);
    ffn2_kernel<<<dim3(8, 192, 3), dim3(256), 0, stream>>>(hbuf, W2t, Ws2t, counts, offs, ybuf);
    mix_kernel<<<dim3(TNUM), dim3(192), 0, stream>>>(ybuf, inv, tokp, offs, b2, bs2, scal, (float*)d_out);
}